// Round 4
// baseline (229.930 us; speedup 1.0000x reference)
//
#include <hip/hip_runtime.h>
#include <hip/hip_bf16.h>

#define NN 100000
#define NE 1600000
#define NBUCK 391   // ceil(NN / 256)
#define CAP 5056    // per-bucket edge capacity (expected 4096, sigma~64; mean+15sigma)
#define CHUNK 2048
#define PBLOCKS 782   // ceil(NE / CHUNK)
#define MMBLOCKS 1563 // ceil(NN / 64)
#define BCUR_STRIDE 16  // one counter per 64B line to kill same-line atomic serialization

typedef __attribute__((ext_vector_type(8))) short short8;
typedef __attribute__((ext_vector_type(4))) float f32x4;

static __device__ __forceinline__ unsigned short f2bf(float f) {
    unsigned u = __float_as_uint(f);
    unsigned r = (u + 0x7fffu + ((u >> 16) & 1u)) >> 16;
    return (unsigned short)r;
}
static __device__ __forceinline__ float bf_lo(unsigned u) {
    return __uint_as_float(u << 16);
}
static __device__ __forceinline__ float bf_hi(unsigned u) {
    return __uint_as_float(u & 0xffff0000u);
}
static __device__ __forceinline__ void acc8(float* acc, uint4 v, float nm) {
    acc[0] += bf_lo(v.x) * nm; acc[1] += bf_hi(v.x) * nm;
    acc[2] += bf_lo(v.y) * nm; acc[3] += bf_hi(v.y) * nm;
    acc[4] += bf_lo(v.z) * nm; acc[5] += bf_hi(v.z) * nm;
    acc[6] += bf_lo(v.w) * nm; acc[7] += bf_hi(v.w) * nm;
}
static __device__ __forceinline__ void acc8a(float* acc, uint4 v) {
    acc[0] += bf_lo(v.x); acc[1] += bf_hi(v.x);
    acc[2] += bf_lo(v.y); acc[3] += bf_hi(v.y);
    acc[4] += bf_lo(v.z); acc[5] += bf_hi(v.z);
    acc[6] += bf_lo(v.w); acc[7] += bf_hi(v.w);
}

// ---- simple unroll-4 aggregation (R1-proven shape), 32-bit byte addressing --
// SCALED=true: h rows are pre-scaled by dinv[src]; no per-edge dinv gather.
// hb is the per-lane byte base (h + sl*16B); row byte offset = src << 7.
template<bool SCALED>
static __device__ __forceinline__ void agg_loop(const unsigned char* hb,
                                                const int* __restrict__ esrc,
                                                const float* __restrict__ dinv,
                                                int start, int cnt, float dn,
                                                float* acc) {
    int i = 0;
    for (; i + 4 <= cnt; i += 4) {
        int s0 = esrc[start + i];
        int s1 = esrc[start + i + 1];
        int s2 = esrc[start + i + 2];
        int s3 = esrc[start + i + 3];
        uint4 w0 = *(const uint4*)(hb + ((unsigned)s0 << 7));
        uint4 w1 = *(const uint4*)(hb + ((unsigned)s1 << 7));
        uint4 w2 = *(const uint4*)(hb + ((unsigned)s2 << 7));
        uint4 w3 = *(const uint4*)(hb + ((unsigned)s3 << 7));
        if constexpr (SCALED) {
            acc8a(acc, w0); acc8a(acc, w1); acc8a(acc, w2); acc8a(acc, w3);
        } else {
            float n0 = dinv[s0] * dn, n1 = dinv[s1] * dn;
            float n2 = dinv[s2] * dn, n3 = dinv[s3] * dn;
            acc8(acc, w0, n0); acc8(acc, w1, n1); acc8(acc, w2, n2); acc8(acc, w3, n3);
        }
    }
    for (; i < cnt; ++i) {
        int s0 = esrc[start + i];
        uint4 w0 = *(const uint4*)(hb + ((unsigned)s0 << 7));
        if constexpr (SCALED) {
            acc8a(acc, w0);
        } else {
            float n0 = dinv[s0] * dn;
            acc8(acc, w0, n0);
        }
    }
}

// ---------- FAT: blocks [0,PBLOCKS) = edge partition (1-pass); rest = x@W1 ----
// bucket = dst >> 8; pack = (src<<8)|(dst&255)
__global__ __launch_bounds__(256) void k_fat(const int* __restrict__ ei,
                                             int* __restrict__ bcur,
                                             unsigned* __restrict__ ebuf,
                                             const float* __restrict__ x,
                                             const float* __restrict__ W1,
                                             unsigned short* __restrict__ hout) {
    __shared__ __attribute__((aligned(16))) unsigned char smem[19584];  // max(mm Wt 17408, part 19532)
    int tid = threadIdx.x;
    if (blockIdx.x < PBLOCKS) {
        // layout: lexc[391]@0 (counts then exclusive scan), lbase[391]@1564,
        // sv[2048]@3128, sd[2048]@11320, wscan[4]@19512, sTot@19528
        int* lexc  = (int*)smem;
        int* lbase = (int*)(smem + 1564);
        unsigned* sv = (unsigned*)(smem + 3128);
        int* sd    = (int*)(smem + 11320);
        int* wscan = (int*)(smem + 19512);
        int* sTot  = (int*)(smem + 19528);

        int e0 = blockIdx.x * CHUNK;
        for (int i = tid; i < NBUCK; i += 256) lexc[i] = 0;
        __syncthreads();
        int bs[8]; int rs[8]; unsigned ps[8];
        #pragma unroll
        for (int k = 0; k < 8; ++k) {
            int e = e0 + k * 256 + tid;
            bs[k] = -1;
            if (e < NE) {
                int d = ei[NE + e];
                int s = ei[e];
                int b = d >> 8;
                bs[k] = b;
                rs[k] = atomicAdd(&lexc[b], 1);     // local rank (single LDS pass)
                ps[k] = ((unsigned)s << 8) | (unsigned)(d & 255);
            }
        }
        __syncthreads();
        // thread t owns buckets 2t, 2t+1: block-wide exclusive scan of counts
        int b0i = 2 * tid, b1i = 2 * tid + 1;
        int c0 = (b0i < NBUCK) ? lexc[b0i] : 0;
        int c1 = (b1i < NBUCK) ? lexc[b1i] : 0;
        int v = c0 + c1;
        int lane = tid & 63;
        int incl = v;
        #pragma unroll
        for (int off = 1; off < 64; off <<= 1) {
            int t = __shfl_up(incl, off, 64);
            if (lane >= off) incl += t;
        }
        if (lane == 63) wscan[tid >> 6] = incl;
        // global within-bucket offsets (padded: each counter on its own 64B line)
        int gb0 = 0, gb1 = 0;
        if (c0) gb0 = atomicAdd(&bcur[b0i * BCUR_STRIDE], c0);
        if (c1) gb1 = atomicAdd(&bcur[b1i * BCUR_STRIDE], c1);
        __syncthreads();
        if (tid == 0) {
            int a = 0;
            #pragma unroll
            for (int w = 0; w < 4; ++w) { int t = wscan[w]; wscan[w] = a; a += t; }
            *sTot = a;
        }
        __syncthreads();
        int ex = incl - v + wscan[tid >> 6];
        if (b0i < NBUCK) { lexc[b0i] = ex;      lbase[b0i] = gb0; }
        if (b1i < NBUCK) { lexc[b1i] = ex + c0; lbase[b1i] = gb1; }
        __syncthreads();
        // scatter into LDS, bucket-major
        #pragma unroll
        for (int k = 0; k < 8; ++k) {
            if (bs[k] >= 0) {
                int b = bs[k];
                int slot = lexc[b] + rs[k];
                int pos  = lbase[b] + rs[k];
                sv[slot] = ps[k];
                sd[slot] = (pos < CAP) ? b * CAP + pos : -1;  // safety clamp; never hit
            }
        }
        __syncthreads();
        int V = *sTot;
        for (int j = tid; j < V; j += 256) {
            int d = sd[j];
            if (d >= 0) ebuf[d] = sv[j];
        }
    } else {
        // ---- mm128: h1 = x @ W1 -> bf16 (R1 64-rows/block shape, VGPR 48) ----
        constexpr int K = 128, KP = K + 8;
        unsigned short* Wt = (unsigned short*)smem;  // 64 * 136
        for (int idx = tid; idx < K * 64; idx += 256) {
            int k = idx >> 6, n = idx & 63;
            Wt[n * KP + k] = f2bf(W1[idx]);
        }
        __syncthreads();
        int wave = tid >> 6, lane = tid & 63;
        int m = lane & 15, q = lane >> 4;
        int n0 = (blockIdx.x - PBLOCKS) * 64 + wave * 16;
        f32x4 acc[4] = {{0.f,0.f,0.f,0.f},{0.f,0.f,0.f,0.f},{0.f,0.f,0.f,0.f},{0.f,0.f,0.f,0.f}};
        int row = n0 + m;
        int rowc = row < NN ? row : NN - 1;
        const float* xr = x + (long)rowc * K;
        #pragma unroll
        for (int kk = 0; kk < K / 32; ++kk) {
            const float4* p = (const float4*)(xr + kk * 32 + q * 8);
            float4 v0 = p[0], v1 = p[1];
            float xv[8] = {v0.x, v0.y, v0.z, v0.w, v1.x, v1.y, v1.z, v1.w};
            short8 afrag;
            #pragma unroll
            for (int i2 = 0; i2 < 8; ++i2) afrag[i2] = (short)f2bf(xv[i2]);
            #pragma unroll
            for (int nt = 0; nt < 4; ++nt) {
                const short8* bp = (const short8*)&Wt[(nt * 16 + m) * KP + kk * 32 + q * 8];
                acc[nt] = __builtin_amdgcn_mfma_f32_16x16x32_bf16(afrag, *bp, acc[nt], 0, 0, 0);
            }
        }
        // D layout: col=lane&15, row=(lane>>4)*4+reg  [m89-verified]
        #pragma unroll
        for (int reg = 0; reg < 4; ++reg) {
            int node = n0 + q * 4 + reg;
            if (node < NN) {
                #pragma unroll
                for (int nt = 0; nt < 4; ++nt)
                    hout[(long)node * 64 + nt * 16 + m] = f2bf(acc[nt][reg]);
            }
        }
    }
}

// one block (256 thr) per bucket, single ebuf pass with register stash.
// edges within each node's segment are sorted by src-tile (tile = src>>14)
// key = (dst_local<<3)|tile; kstart[key] = start.
// rowinfo[node] = (start << 11) | degree   (start < 2^21, deg < 2^11)
// NEW: also accumulates the global degree histogram (LDS-hist -> padded global
// bins) for the degree-sorted node permutation.
__global__ __launch_bounds__(256) void k_build(const int* __restrict__ bcur,
                                               const unsigned* __restrict__ ebuf,
                                               unsigned* __restrict__ rowinfo,
                                               float* __restrict__ dinv,
                                               int* __restrict__ esrc,
                                               int* __restrict__ dhist) {
    __shared__ int cnt[2048];
    __shared__ int kstart[2048];
    __shared__ int wsum[4];
    __shared__ int lhist[256];
    int tid = threadIdx.x;
    int base = blockIdx.x * CAP;
    int nedge = bcur[blockIdx.x * BCUR_STRIDE];
    if (nedge > CAP) nedge = CAP;
    #pragma unroll
    for (int t = 0; t < 8; ++t) cnt[(tid << 3) | t] = 0;
    lhist[tid] = 0;
    __syncthreads();
    int st[20];      // (rank<<11) | key, or -1
    int ssrc[20];    // src node id
    #pragma unroll
    for (int k = 0; k < 20; ++k) {
        int j = tid + k * 256;
        st[k] = -1;
        if (j < nedge) {
            unsigned p = ebuf[base + j];
            int dl = (int)(p & 255u);
            int s = (int)(p >> 8);
            int key = (dl << 3) | (s >> 14);
            int r = atomicAdd(&cnt[key], 1);
            st[k] = (r << 11) | key;
            ssrc[k] = s;
        }
    }
    __syncthreads();
    // thread tid owns node tid: serial scan over its 8 tile counts
    int c[8];
    int v = 0;
    #pragma unroll
    for (int t = 0; t < 8; ++t) { c[t] = cnt[(tid << 3) | t]; v += c[t]; }
    int lane = tid & 63;
    int incl = v;
    #pragma unroll
    for (int off = 1; off < 64; off <<= 1) {
        int t = __shfl_up(incl, off, 64);
        if (lane >= off) incl += t;
    }
    if (lane == 63) wsum[tid >> 6] = incl;
    __syncthreads();
    if (tid == 0) {
        int a = 0;
        #pragma unroll
        for (int w = 0; w < 4; ++w) { int t = wsum[w]; wsum[w] = a; a += t; }
    }
    __syncthreads();
    int ex = incl - v + wsum[tid >> 6];
    int node = blockIdx.x * 256 + tid;
    if (node < NN) {
        rowinfo[node] = ((unsigned)(base + ex) << 11) | (unsigned)v;
        dinv[node] = rsqrtf((float)(v + 1));  // +1 self-loop
        atomicAdd(&lhist[v < 255 ? v : 255], 1);
    }
    int off = base + ex;
    #pragma unroll
    for (int t = 0; t < 8; ++t) { kstart[(tid << 3) | t] = off; off += c[t]; }
    __syncthreads();
    #pragma unroll
    for (int k = 0; k < 20; ++k) {
        if (st[k] >= 0)
            esrc[kstart[st[k] & 2047] + (st[k] >> 11)] = ssrc[k];
    }
    // flush degree histogram (padded: one bin per 64B line)
    int hc = lhist[tid];
    if (hc) atomicAdd(&dhist[tid * 16], hc);
}

// ---------- degree-sorted node permutation (counting sort) -------------------
// perm[i] = node, ordered by degree. Each wave in the agg kernels then gets
// 8 near-equal-degree nodes -> trip count = max(8 degrees) ~= mean, killing
// the ~36% exec-mask waste of random grouping (Poisson(16): E[max8]=21.7).
__global__ __launch_bounds__(256) void k_perm(const unsigned* __restrict__ rowinfo,
                                              const int* __restrict__ dhist,
                                              int* __restrict__ binpos,
                                              int* __restrict__ perm) {
    __shared__ int lh[256];   // per-bin local counts / ranks
    __shared__ int gb[256];   // per-bin global base for this block
    __shared__ int wsum[4];
    int tid = threadIdx.x;
    lh[tid] = 0;
    __syncthreads();
    int node = blockIdx.x * 256 + tid;
    int bin = 0, rank = 0;
    bool live = node < NN;
    if (live) {
        int deg = (int)(rowinfo[node] & 2047u);
        bin = deg < 255 ? deg : 255;
        rank = atomicAdd(&lh[bin], 1);
    }
    __syncthreads();
    int c = lh[tid];
    // exclusive scan of the GLOBAL histogram (bin tid) -> dbase
    int h = dhist[tid * 16];
    int lane = tid & 63;
    int incl = h;
    #pragma unroll
    for (int off = 1; off < 64; off <<= 1) {
        int t = __shfl_up(incl, off, 64);
        if (lane >= off) incl += t;
    }
    if (lane == 63) wsum[tid >> 6] = incl;
    __syncthreads();
    if (tid == 0) {
        int a = 0;
        #pragma unroll
        for (int w = 0; w < 4; ++w) { int t = wsum[w]; wsum[w] = a; a += t; }
    }
    __syncthreads();
    int dbase = incl - h + wsum[tid >> 6];
    gb[tid] = dbase + (c ? atomicAdd(&binpos[tid * 16], c) : 0);
    __syncthreads();
    if (live) perm[gb[bin] + rank] = node;
}

// ---------- fused: layer-1 agg (32 nodes/block) + h2 = prelu(agg1)@W2 --------
// Nodes assigned via degree-sorted perm (uniform trip count per wave).
// h2 output is PRE-SCALED by dinv[node] -> k_agg2 needs no per-edge dinv gather.
__global__ __launch_bounds__(256) void k_aggmm(const unsigned* __restrict__ rowinfo,
                                               const int* __restrict__ esrc,
                                               const unsigned short* __restrict__ h,
                                               const float* __restrict__ dinv,
                                               const float* __restrict__ bias,
                                               const float* __restrict__ alpha,
                                               const float* __restrict__ W2,
                                               const int* __restrict__ perm,
                                               unsigned short* __restrict__ hout2) {
    __shared__ unsigned short Wt[64 * 72];    // W2 staged: Wt[n*72+k]
    __shared__ unsigned short aggs[32 * 72];  // 32 node-rows of bf16 agg (+8 pad)
    __shared__ float dnv[32];                 // per-node dinv for epilogue scaling
    __shared__ int pnode[32];                 // per-row node id for epilogue scatter
    int tid = threadIdx.x;
    for (int idx = tid; idx < 64 * 64; idx += 256) {
        int k = idx >> 6, n = idx & 63;
        Wt[n * 72 + k] = f2bf(W2[idx]);
    }
    int sl = tid & 7;
    int ln = tid >> 3;                  // 0..31 local row
    int node = perm[blockIdx.x * 32 + ln];
    unsigned u = rowinfo[node];
    int start = (int)(u >> 11);
    int cnt = (int)(u & 2047u);
    float dn = dinv[node];
    if (sl == 0) { dnv[ln] = dn; pnode[ln] = node; }
    const unsigned char* hb = (const unsigned char*)h + sl * 16;

    float acc[8];
    {   // self-loop
        uint4 hw = *(const uint4*)(hb + ((unsigned)node << 7));
        float d2 = dn * dn;
        acc[0] = bf_lo(hw.x) * d2; acc[1] = bf_hi(hw.x) * d2;
        acc[2] = bf_lo(hw.y) * d2; acc[3] = bf_hi(hw.y) * d2;
        acc[4] = bf_lo(hw.z) * d2; acc[5] = bf_hi(hw.z) * d2;
        acc[6] = bf_lo(hw.w) * d2; acc[7] = bf_hi(hw.w) * d2;
    }
    agg_loop<false>(hb, esrc, dinv, start, cnt, dn, acc);

    float4 blo = *(const float4*)(bias + sl * 8);
    float4 bhi = *(const float4*)(bias + sl * 8 + 4);
    float4 alo = *(const float4*)(alpha + sl * 8);
    float4 ahi = *(const float4*)(alpha + sl * 8 + 4);
    float bb[8] = {blo.x, blo.y, blo.z, blo.w, bhi.x, bhi.y, bhi.z, bhi.w};
    float aa[8] = {alo.x, alo.y, alo.z, alo.w, ahi.x, ahi.y, ahi.z, ahi.w};
    #pragma unroll
    for (int j = 0; j < 8; ++j) {
        float v = acc[j] + bb[j];
        acc[j] = v >= 0.f ? v : aa[j] * v;
    }
    uint4 pk;
    pk.x = (unsigned)f2bf(acc[0]) | ((unsigned)f2bf(acc[1]) << 16);
    pk.y = (unsigned)f2bf(acc[2]) | ((unsigned)f2bf(acc[3]) << 16);
    pk.z = (unsigned)f2bf(acc[4]) | ((unsigned)f2bf(acc[5]) << 16);
    pk.w = (unsigned)f2bf(acc[6]) | ((unsigned)f2bf(acc[7]) << 16);
    *(uint4*)&aggs[ln * 72 + sl * 8] = pk;
    __syncthreads();

    // MFMA: waves 0,1 compute 16 rows each: [16x64] @ [64x64]
    int wave = tid >> 6;
    if (wave < 2) {
        int lane = tid & 63;
        int m = lane & 15, q = lane >> 4;
        int row = wave * 16 + m;
        f32x4 c2[4] = {{0.f,0.f,0.f,0.f},{0.f,0.f,0.f,0.f},{0.f,0.f,0.f,0.f},{0.f,0.f,0.f,0.f}};
        #pragma unroll
        for (int kk = 0; kk < 2; ++kk) {
            short8 afrag = *(const short8*)&aggs[row * 72 + kk * 32 + q * 8];
            #pragma unroll
            for (int nt = 0; nt < 4; ++nt) {
                const short8* bp = (const short8*)&Wt[(nt * 16 + m) * 72 + kk * 32 + q * 8];
                c2[nt] = __builtin_amdgcn_mfma_f32_16x16x32_bf16(afrag, *bp, c2[nt], 0, 0, 0);
            }
        }
        #pragma unroll
        for (int reg = 0; reg < 4; ++reg) {
            int rr = wave * 16 + q * 4 + reg;
            int nd = pnode[rr];
            float dv = dnv[rr];
            #pragma unroll
            for (int nt = 0; nt < 4; ++nt)
                hout2[(long)nd * 64 + nt * 16 + m] = f2bf(c2[nt][reg] * dv);
        }
    }
}

// ---------- final aggregation: 8 lanes/node, fp32 out ------------------------
// h is pre-scaled by dinv[src]: per-edge work = load + unpack-add only;
// uniform dn applied once at the end. Degree-sorted node assignment via perm.
__global__ __launch_bounds__(256) void k_agg2(const unsigned* __restrict__ rowinfo,
                                              const int* __restrict__ esrc,
                                              const unsigned short* __restrict__ h,
                                              const float* __restrict__ dinv,
                                              const float* __restrict__ bias,
                                              const float* __restrict__ alpha,
                                              const int* __restrict__ perm,
                                              float* __restrict__ out) {
    int sl = threadIdx.x & 7;
    int node = perm[blockIdx.x * 32 + (threadIdx.x >> 3)];
    unsigned u = rowinfo[node];
    int start = (int)(u >> 11);
    int cnt = (int)(u & 2047u);
    float dn = dinv[node];
    const unsigned char* hb = (const unsigned char*)h + sl * 16;

    float acc[8];
    {   // self-loop: h[node] already carries dinv[node]; one more *dn at the end
        uint4 hw = *(const uint4*)(hb + ((unsigned)node << 7));
        acc[0] = bf_lo(hw.x); acc[1] = bf_hi(hw.x);
        acc[2] = bf_lo(hw.y); acc[3] = bf_hi(hw.y);
        acc[4] = bf_lo(hw.z); acc[5] = bf_hi(hw.z);
        acc[6] = bf_lo(hw.w); acc[7] = bf_hi(hw.w);
    }
    agg_loop<true>(hb, esrc, dinv, start, cnt, dn, acc);

    float4 blo = *(const float4*)(bias + sl * 8);
    float4 bhi = *(const float4*)(bias + sl * 8 + 4);
    float4 alo = *(const float4*)(alpha + sl * 8);
    float4 ahi = *(const float4*)(alpha + sl * 8 + 4);
    float bb[8] = {blo.x, blo.y, blo.z, blo.w, bhi.x, bhi.y, bhi.z, bhi.w};
    float aa[8] = {alo.x, alo.y, alo.z, alo.w, ahi.x, ahi.y, ahi.z, ahi.w};
    #pragma unroll
    for (int j = 0; j < 8; ++j) {
        float v = acc[j] * dn + bb[j];
        acc[j] = v >= 0.f ? v : aa[j] * v;
    }
    float* op = out + (long)node * 64 + sl * 8;
    *(float4*)op = make_float4(acc[0], acc[1], acc[2], acc[3]);
    *(float4*)(op + 4) = make_float4(acc[4], acc[5], acc[6], acc[7]);
}

extern "C" void kernel_launch(void* const* d_in, const int* in_sizes, int n_in,
                              void* d_out, int out_size, void* d_ws, size_t ws_size,
                              hipStream_t stream) {
    const float* x     = (const float*)d_in[0];
    const int*   ei    = (const int*)d_in[1];
    const float* W1    = (const float*)d_in[2];
    const float* b1    = (const float*)d_in[3];
    const float* W2    = (const float*)d_in[4];
    const float* b2    = (const float*)d_in[5];
    const float* alpha = (const float*)d_in[6];
    float* out = (float*)d_out;

    char* ws = (char*)d_ws;
    float*    dinv      = (float*)(ws);                      //        0: 400,384
    unsigned* rowinfo   = (unsigned*)(ws + 400384);          //   400384: 400,384
    int*      bcur      = (int*)(ws + 800768);               //   800768: 25,088 (391*64B)
    int*      dhist     = (int*)(ws + 825856);               //   825856: 16,384 (256*64B)
    int*      binpos    = (int*)(ws + 842240);               //   842240: 16,384 (256*64B)
    int*      perm      = (int*)(ws + 858624);               //   858624: 400,384
    int*      esrc      = (int*)(ws + 1259008);              //  1259008: 7,907,584 (391*CAP*4)
    unsigned short* hbf = (unsigned short*)(ws + 9166592);   //  9166592: 12,800,000
    unsigned* ebuf      = (unsigned*)(ws + 21966592);        // 21966592: region max(7.9M, 12.8M)
    unsigned short* hbf2 = (unsigned short*)(ws + 21966592); // alias ebuf (dead after k_build)
    // total: 34,766,592 B

    // zero bcur + dhist + binpos in one shot (contiguous)
    (void)hipMemsetAsync(bcur, 0, 25088 + 16384 + 16384, stream);
    // edge partition (782 blocks, single-pass) overlapped with x@W1 (1563 blocks)
    k_fat<<<PBLOCKS + MMBLOCKS, 256, 0, stream>>>(ei, bcur, ebuf, x, W1, hbf);
    k_build<<<NBUCK, 256, 0, stream>>>(bcur, ebuf, rowinfo, dinv, esrc, dhist);
    // degree-sorted node permutation (counting sort; any order within a bin)
    k_perm<<<NBUCK, 256, 0, stream>>>(rowinfo, dhist, binpos, perm);
    // layer-1 agg fused with layer-2 matmul (h2 -> hbf2, aliases dead ebuf)
    k_aggmm<<<NN / 32, 256, 0, stream>>>(rowinfo, esrc, hbf, dinv, b1, alpha, W2, perm, hbf2);
    // layer-2 aggregation -> fp32 out
    k_agg2<<<NN / 32, 256, 0, stream>>>(rowinfo, esrc, hbf2, dinv, b2, alpha, perm, out);
}

// Round 5
// 213.218 us; speedup vs baseline: 1.0784x; 1.0784x over previous
//
#include <hip/hip_runtime.h>
#include <hip/hip_bf16.h>

#define NN 100000
#define NE 1600000
#define NBUCK 391   // ceil(NN / 256)
#define CAP 5056    // per-bucket edge capacity (expected 4096, sigma~64; mean+15sigma)
#define CHUNK 2048
#define PBLOCKS 782   // ceil(NE / CHUNK)
#define MMBLOCKS 1563 // ceil(NN / 64)
#define BCUR_STRIDE 16  // one counter per 64B line to kill same-line atomic serialization

typedef __attribute__((ext_vector_type(8))) short short8;
typedef __attribute__((ext_vector_type(4))) float f32x4;

static __device__ __forceinline__ unsigned short f2bf(float f) {
    unsigned u = __float_as_uint(f);
    unsigned r = (u + 0x7fffu + ((u >> 16) & 1u)) >> 16;
    return (unsigned short)r;
}
static __device__ __forceinline__ float bf_lo(unsigned u) {
    return __uint_as_float(u << 16);
}
static __device__ __forceinline__ float bf_hi(unsigned u) {
    return __uint_as_float(u & 0xffff0000u);
}
static __device__ __forceinline__ void acc8(float* acc, uint4 v, float nm) {
    acc[0] += bf_lo(v.x) * nm; acc[1] += bf_hi(v.x) * nm;
    acc[2] += bf_lo(v.y) * nm; acc[3] += bf_hi(v.y) * nm;
    acc[4] += bf_lo(v.z) * nm; acc[5] += bf_hi(v.z) * nm;
    acc[6] += bf_lo(v.w) * nm; acc[7] += bf_hi(v.w) * nm;
}
static __device__ __forceinline__ void acc8a(float* acc, uint4 v) {
    acc[0] += bf_lo(v.x); acc[1] += bf_hi(v.x);
    acc[2] += bf_lo(v.y); acc[3] += bf_hi(v.y);
    acc[4] += bf_lo(v.z); acc[5] += bf_hi(v.z);
    acc[6] += bf_lo(v.w); acc[7] += bf_hi(v.w);
}

// ---- simple unroll-4 aggregation (R1-proven shape), 32-bit byte addressing --
// SCALED=true: h rows are pre-scaled by dinv[src]; no per-edge dinv gather.
// hb is the per-lane byte base (h + sl*16B); row byte offset = src << 7.
template<bool SCALED>
static __device__ __forceinline__ void agg_loop(const unsigned char* hb,
                                                const int* __restrict__ esrc,
                                                const float* __restrict__ dinv,
                                                int start, int cnt, float dn,
                                                float* acc) {
    int i = 0;
    for (; i + 4 <= cnt; i += 4) {
        int s0 = esrc[start + i];
        int s1 = esrc[start + i + 1];
        int s2 = esrc[start + i + 2];
        int s3 = esrc[start + i + 3];
        uint4 w0 = *(const uint4*)(hb + ((unsigned)s0 << 7));
        uint4 w1 = *(const uint4*)(hb + ((unsigned)s1 << 7));
        uint4 w2 = *(const uint4*)(hb + ((unsigned)s2 << 7));
        uint4 w3 = *(const uint4*)(hb + ((unsigned)s3 << 7));
        if constexpr (SCALED) {
            acc8a(acc, w0); acc8a(acc, w1); acc8a(acc, w2); acc8a(acc, w3);
        } else {
            float n0 = dinv[s0] * dn, n1 = dinv[s1] * dn;
            float n2 = dinv[s2] * dn, n3 = dinv[s3] * dn;
            acc8(acc, w0, n0); acc8(acc, w1, n1); acc8(acc, w2, n2); acc8(acc, w3, n3);
        }
    }
    for (; i < cnt; ++i) {
        int s0 = esrc[start + i];
        uint4 w0 = *(const uint4*)(hb + ((unsigned)s0 << 7));
        if constexpr (SCALED) {
            acc8a(acc, w0);
        } else {
            float n0 = dinv[s0] * dn;
            acc8(acc, w0, n0);
        }
    }
}

// ---------- FAT: blocks [0,PBLOCKS) = edge partition (1-pass); rest = x@W1 ----
// bucket = dst >> 8; pack = (src<<8)|(dst&255)
// R1-proven: padded bcur (1 counter/line) + LDS bucket-sort so ebuf stores go
// out bucket-major (wave store ~12 lines instead of 64).
__global__ __launch_bounds__(256) void k_fat(const int* __restrict__ ei,
                                             int* __restrict__ bcur,
                                             unsigned* __restrict__ ebuf,
                                             const float* __restrict__ x,
                                             const float* __restrict__ W1,
                                             unsigned short* __restrict__ hout) {
    __shared__ __attribute__((aligned(16))) unsigned char smem[19584];  // max(mm Wt 17408, part 19532)
    int tid = threadIdx.x;
    if (blockIdx.x < PBLOCKS) {
        // layout: lexc[391]@0 (counts then exclusive scan), lbase[391]@1564,
        // sv[2048]@3128, sd[2048]@11320, wscan[4]@19512, sTot@19528
        int* lexc  = (int*)smem;
        int* lbase = (int*)(smem + 1564);
        unsigned* sv = (unsigned*)(smem + 3128);
        int* sd    = (int*)(smem + 11320);
        int* wscan = (int*)(smem + 19512);
        int* sTot  = (int*)(smem + 19528);

        int e0 = blockIdx.x * CHUNK;
        for (int i = tid; i < NBUCK; i += 256) lexc[i] = 0;
        __syncthreads();
        int bs[8]; int rs[8]; unsigned ps[8];
        #pragma unroll
        for (int k = 0; k < 8; ++k) {
            int e = e0 + k * 256 + tid;
            bs[k] = -1;
            if (e < NE) {
                int d = ei[NE + e];
                int s = ei[e];
                int b = d >> 8;
                bs[k] = b;
                rs[k] = atomicAdd(&lexc[b], 1);     // local rank (single LDS pass)
                ps[k] = ((unsigned)s << 8) | (unsigned)(d & 255);
            }
        }
        __syncthreads();
        // thread t owns buckets 2t, 2t+1: block-wide exclusive scan of counts
        int b0i = 2 * tid, b1i = 2 * tid + 1;
        int c0 = (b0i < NBUCK) ? lexc[b0i] : 0;
        int c1 = (b1i < NBUCK) ? lexc[b1i] : 0;
        int v = c0 + c1;
        int lane = tid & 63;
        int incl = v;
        #pragma unroll
        for (int off = 1; off < 64; off <<= 1) {
            int t = __shfl_up(incl, off, 64);
            if (lane >= off) incl += t;
        }
        if (lane == 63) wscan[tid >> 6] = incl;
        // global within-bucket offsets (padded: each counter on its own 64B line)
        int gb0 = 0, gb1 = 0;
        if (c0) gb0 = atomicAdd(&bcur[b0i * BCUR_STRIDE], c0);
        if (c1) gb1 = atomicAdd(&bcur[b1i * BCUR_STRIDE], c1);
        __syncthreads();
        if (tid == 0) {
            int a = 0;
            #pragma unroll
            for (int w = 0; w < 4; ++w) { int t = wscan[w]; wscan[w] = a; a += t; }
            *sTot = a;
        }
        __syncthreads();
        int ex = incl - v + wscan[tid >> 6];
        if (b0i < NBUCK) { lexc[b0i] = ex;      lbase[b0i] = gb0; }
        if (b1i < NBUCK) { lexc[b1i] = ex + c0; lbase[b1i] = gb1; }
        __syncthreads();
        // scatter into LDS, bucket-major
        #pragma unroll
        for (int k = 0; k < 8; ++k) {
            if (bs[k] >= 0) {
                int b = bs[k];
                int slot = lexc[b] + rs[k];
                int pos  = lbase[b] + rs[k];
                sv[slot] = ps[k];
                sd[slot] = (pos < CAP) ? b * CAP + pos : -1;  // safety clamp; never hit
            }
        }
        __syncthreads();
        int V = *sTot;
        for (int j = tid; j < V; j += 256) {
            int d = sd[j];
            if (d >= 0) ebuf[d] = sv[j];
        }
    } else {
        // ---- mm128: h1 = x @ W1 -> bf16 (64 rows/block, R1-proven) ----
        constexpr int K = 128, KP = K + 8;
        unsigned short* Wt = (unsigned short*)smem;  // 64 * 136
        for (int idx = tid; idx < K * 64; idx += 256) {
            int k = idx >> 6, n = idx & 63;
            Wt[n * KP + k] = f2bf(W1[idx]);
        }
        __syncthreads();
        int wave = tid >> 6, lane = tid & 63;
        int m = lane & 15, q = lane >> 4;
        int n0 = (blockIdx.x - PBLOCKS) * 64 + wave * 16;
        f32x4 acc[4] = {{0.f,0.f,0.f,0.f},{0.f,0.f,0.f,0.f},{0.f,0.f,0.f,0.f},{0.f,0.f,0.f,0.f}};
        int row = n0 + m;
        int rowc = row < NN ? row : NN - 1;
        const float* xr = x + (long)rowc * K;
        #pragma unroll
        for (int kk = 0; kk < K / 32; ++kk) {
            const float4* p = (const float4*)(xr + kk * 32 + q * 8);
            float4 v0 = p[0], v1 = p[1];
            float xv[8] = {v0.x, v0.y, v0.z, v0.w, v1.x, v1.y, v1.z, v1.w};
            short8 afrag;
            #pragma unroll
            for (int i2 = 0; i2 < 8; ++i2) afrag[i2] = (short)f2bf(xv[i2]);
            #pragma unroll
            for (int nt = 0; nt < 4; ++nt) {
                const short8* bp = (const short8*)&Wt[(nt * 16 + m) * KP + kk * 32 + q * 8];
                acc[nt] = __builtin_amdgcn_mfma_f32_16x16x32_bf16(afrag, *bp, acc[nt], 0, 0, 0);
            }
        }
        // D layout: col=lane&15, row=(lane>>4)*4+reg  [m89-verified]
        #pragma unroll
        for (int reg = 0; reg < 4; ++reg) {
            int node = n0 + q * 4 + reg;
            if (node < NN) {
                #pragma unroll
                for (int nt = 0; nt < 4; ++nt)
                    hout[(long)node * 64 + nt * 16 + m] = f2bf(acc[nt][reg]);
            }
        }
    }
}

// one block (256 thr) per bucket, single ebuf pass with register stash.
// edges within each node's segment are sorted by src-tile (tile = src>>14)
// key = (dst_local<<3)|tile; kstart[key] = start.
// rowinfo[node] = (start << 11) | degree   (start < 2^21, deg < 2^11)
__global__ __launch_bounds__(256) void k_build(const int* __restrict__ bcur,
                                               const unsigned* __restrict__ ebuf,
                                               unsigned* __restrict__ rowinfo,
                                               float* __restrict__ dinv,
                                               int* __restrict__ esrc) {
    __shared__ int cnt[2048];
    __shared__ int kstart[2048];
    __shared__ int wsum[4];
    int tid = threadIdx.x;
    int base = blockIdx.x * CAP;
    int nedge = bcur[blockIdx.x * BCUR_STRIDE];
    if (nedge > CAP) nedge = CAP;
    #pragma unroll
    for (int t = 0; t < 8; ++t) cnt[(tid << 3) | t] = 0;
    __syncthreads();
    int st[20];      // (rank<<11) | key, or -1
    int ssrc[20];    // src node id
    #pragma unroll
    for (int k = 0; k < 20; ++k) {
        int j = tid + k * 256;
        st[k] = -1;
        if (j < nedge) {
            unsigned p = ebuf[base + j];
            int dl = (int)(p & 255u);
            int s = (int)(p >> 8);
            int key = (dl << 3) | (s >> 14);
            int r = atomicAdd(&cnt[key], 1);
            st[k] = (r << 11) | key;
            ssrc[k] = s;
        }
    }
    __syncthreads();
    // thread tid owns node tid: serial scan over its 8 tile counts
    int c[8];
    int v = 0;
    #pragma unroll
    for (int t = 0; t < 8; ++t) { c[t] = cnt[(tid << 3) | t]; v += c[t]; }
    int lane = tid & 63;
    int incl = v;
    #pragma unroll
    for (int off = 1; off < 64; off <<= 1) {
        int t = __shfl_up(incl, off, 64);
        if (lane >= off) incl += t;
    }
    if (lane == 63) wsum[tid >> 6] = incl;
    __syncthreads();
    if (tid == 0) {
        int a = 0;
        #pragma unroll
        for (int w = 0; w < 4; ++w) { int t = wsum[w]; wsum[w] = a; a += t; }
    }
    __syncthreads();
    int ex = incl - v + wsum[tid >> 6];
    int node = blockIdx.x * 256 + tid;
    if (node < NN) {
        rowinfo[node] = ((unsigned)(base + ex) << 11) | (unsigned)v;
        dinv[node] = rsqrtf((float)(v + 1));  // +1 self-loop
    }
    int off = base + ex;
    #pragma unroll
    for (int t = 0; t < 8; ++t) { kstart[(tid << 3) | t] = off; off += c[t]; }
    __syncthreads();
    #pragma unroll
    for (int k = 0; k < 20; ++k) {
        if (st[k] >= 0)
            esrc[kstart[st[k] & 2047] + (st[k] >> 11)] = ssrc[k];
    }
}

// ---------- fused: layer-1 agg (32 nodes/block) + h2 = prelu(agg1)@W2 --------
// NN % 32 == 0 so every block is full.
// h2 output is PRE-SCALED by dinv[node] (single bf16 rounding of the product,
// same relative-error profile) -> k_agg2 needs no per-edge dinv gather.
__global__ __launch_bounds__(256) void k_aggmm(const unsigned* __restrict__ rowinfo,
                                               const int* __restrict__ esrc,
                                               const unsigned short* __restrict__ h,
                                               const float* __restrict__ dinv,
                                               const float* __restrict__ bias,
                                               const float* __restrict__ alpha,
                                               const float* __restrict__ W2,
                                               unsigned short* __restrict__ hout2) {
    __shared__ unsigned short Wt[64 * 72];    // W2 staged: Wt[n*72+k]
    __shared__ unsigned short aggs[32 * 72];  // 32 node-rows of bf16 agg (+8 pad)
    __shared__ float dnv[32];                 // per-node dinv for epilogue scaling
    int tid = threadIdx.x;
    for (int idx = tid; idx < 64 * 64; idx += 256) {
        int k = idx >> 6, n = idx & 63;
        Wt[n * 72 + k] = f2bf(W2[idx]);
    }
    int sl = tid & 7;
    int ln = tid >> 3;                  // 0..31 local node
    int node = blockIdx.x * 32 + ln;
    unsigned u = rowinfo[node];
    int start = (int)(u >> 11);
    int cnt = (int)(u & 2047u);
    float dn = dinv[node];
    if (sl == 0) dnv[ln] = dn;
    const unsigned char* hb = (const unsigned char*)h + sl * 16;

    float acc[8];
    {   // self-loop
        uint4 hw = *(const uint4*)(hb + ((unsigned)node << 7));
        float d2 = dn * dn;
        acc[0] = bf_lo(hw.x) * d2; acc[1] = bf_hi(hw.x) * d2;
        acc[2] = bf_lo(hw.y) * d2; acc[3] = bf_hi(hw.y) * d2;
        acc[4] = bf_lo(hw.z) * d2; acc[5] = bf_hi(hw.z) * d2;
        acc[6] = bf_lo(hw.w) * d2; acc[7] = bf_hi(hw.w) * d2;
    }
    agg_loop<false>(hb, esrc, dinv, start, cnt, dn, acc);

    float4 blo = *(const float4*)(bias + sl * 8);
    float4 bhi = *(const float4*)(bias + sl * 8 + 4);
    float4 alo = *(const float4*)(alpha + sl * 8);
    float4 ahi = *(const float4*)(alpha + sl * 8 + 4);
    float bb[8] = {blo.x, blo.y, blo.z, blo.w, bhi.x, bhi.y, bhi.z, bhi.w};
    float aa[8] = {alo.x, alo.y, alo.z, alo.w, ahi.x, ahi.y, ahi.z, ahi.w};
    #pragma unroll
    for (int j = 0; j < 8; ++j) {
        float v = acc[j] + bb[j];
        acc[j] = v >= 0.f ? v : aa[j] * v;
    }
    uint4 pk;
    pk.x = (unsigned)f2bf(acc[0]) | ((unsigned)f2bf(acc[1]) << 16);
    pk.y = (unsigned)f2bf(acc[2]) | ((unsigned)f2bf(acc[3]) << 16);
    pk.z = (unsigned)f2bf(acc[4]) | ((unsigned)f2bf(acc[5]) << 16);
    pk.w = (unsigned)f2bf(acc[6]) | ((unsigned)f2bf(acc[7]) << 16);
    *(uint4*)&aggs[ln * 72 + sl * 8] = pk;
    __syncthreads();

    // MFMA: waves 0,1 compute 16 rows each: [16x64] @ [64x64]
    int wave = tid >> 6;
    if (wave < 2) {
        int lane = tid & 63;
        int m = lane & 15, q = lane >> 4;
        int row = wave * 16 + m;
        f32x4 c2[4] = {{0.f,0.f,0.f,0.f},{0.f,0.f,0.f,0.f},{0.f,0.f,0.f,0.f},{0.f,0.f,0.f,0.f}};
        #pragma unroll
        for (int kk = 0; kk < 2; ++kk) {
            short8 afrag = *(const short8*)&aggs[row * 72 + kk * 32 + q * 8];
            #pragma unroll
            for (int nt = 0; nt < 4; ++nt) {
                const short8* bp = (const short8*)&Wt[(nt * 16 + m) * 72 + kk * 32 + q * 8];
                c2[nt] = __builtin_amdgcn_mfma_f32_16x16x32_bf16(afrag, *bp, c2[nt], 0, 0, 0);
            }
        }
        #pragma unroll
        for (int reg = 0; reg < 4; ++reg) {
            int rr = wave * 16 + q * 4 + reg;
            int nd = blockIdx.x * 32 + rr;
            float dv = dnv[rr];
            #pragma unroll
            for (int nt = 0; nt < 4; ++nt)
                hout2[(long)nd * 64 + nt * 16 + m] = f2bf(c2[nt][reg] * dv);
        }
    }
}

// ---------- final aggregation: 8 lanes/node, fp32 out ------------------------
// h is pre-scaled by dinv[src]: per-edge work = load + unpack-add only;
// uniform dn applied once at the end.
__global__ __launch_bounds__(256) void k_agg2(const unsigned* __restrict__ rowinfo,
                                              const int* __restrict__ esrc,
                                              const unsigned short* __restrict__ h,
                                              const float* __restrict__ dinv,
                                              const float* __restrict__ bias,
                                              const float* __restrict__ alpha,
                                              float* __restrict__ out) {
    int sl = threadIdx.x & 7;
    int node = blockIdx.x * 32 + (threadIdx.x >> 3);
    unsigned u = rowinfo[node];
    int start = (int)(u >> 11);
    int cnt = (int)(u & 2047u);
    float dn = dinv[node];
    const unsigned char* hb = (const unsigned char*)h + sl * 16;

    float acc[8];
    {   // self-loop: h[node] already carries dinv[node]; one more *dn at the end
        uint4 hw = *(const uint4*)(hb + ((unsigned)node << 7));
        acc[0] = bf_lo(hw.x); acc[1] = bf_hi(hw.x);
        acc[2] = bf_lo(hw.y); acc[3] = bf_hi(hw.y);
        acc[4] = bf_lo(hw.z); acc[5] = bf_hi(hw.z);
        acc[6] = bf_lo(hw.w); acc[7] = bf_hi(hw.w);
    }
    agg_loop<true>(hb, esrc, dinv, start, cnt, dn, acc);

    float4 blo = *(const float4*)(bias + sl * 8);
    float4 bhi = *(const float4*)(bias + sl * 8 + 4);
    float4 alo = *(const float4*)(alpha + sl * 8);
    float4 ahi = *(const float4*)(alpha + sl * 8 + 4);
    float bb[8] = {blo.x, blo.y, blo.z, blo.w, bhi.x, bhi.y, bhi.z, bhi.w};
    float aa[8] = {alo.x, alo.y, alo.z, alo.w, ahi.x, ahi.y, ahi.z, ahi.w};
    #pragma unroll
    for (int j = 0; j < 8; ++j) {
        float v = acc[j] * dn + bb[j];
        acc[j] = v >= 0.f ? v : aa[j] * v;
    }
    float* op = out + (long)node * 64 + sl * 8;
    *(float4*)op = make_float4(acc[0], acc[1], acc[2], acc[3]);
    *(float4*)(op + 4) = make_float4(acc[4], acc[5], acc[6], acc[7]);
}

extern "C" void kernel_launch(void* const* d_in, const int* in_sizes, int n_in,
                              void* d_out, int out_size, void* d_ws, size_t ws_size,
                              hipStream_t stream) {
    const float* x     = (const float*)d_in[0];
    const int*   ei    = (const int*)d_in[1];
    const float* W1    = (const float*)d_in[2];
    const float* b1    = (const float*)d_in[3];
    const float* W2    = (const float*)d_in[4];
    const float* b2    = (const float*)d_in[5];
    const float* alpha = (const float*)d_in[6];
    float* out = (float*)d_out;

    char* ws = (char*)d_ws;
    float*    dinv      = (float*)(ws);                      //        0: 400,384
    unsigned* rowinfo   = (unsigned*)(ws + 400384);          //   400384: 400,384
    int*      bcur      = (int*)(ws + 800768);               //   800768: 25,088 (391*64B, padded)
    int*      esrc      = (int*)(ws + 825856);               //   825856: 7,907,584 (391*CAP*4)
    unsigned short* hbf = (unsigned short*)(ws + 8733440);   //  8733440: 12,800,000
    unsigned* ebuf      = (unsigned*)(ws + 21533440);        // 21533440: region max(7.9M, 12.8M)
    unsigned short* hbf2 = (unsigned short*)(ws + 21533440); // alias ebuf (dead after k_build)
    // total: 34,333,440 B

    (void)hipMemsetAsync(bcur, 0, NBUCK * BCUR_STRIDE * sizeof(int), stream);
    // edge partition (782 blocks, single-pass) overlapped with x@W1 (1563 blocks)
    k_fat<<<PBLOCKS + MMBLOCKS, 256, 0, stream>>>(ei, bcur, ebuf, x, W1, hbf);
    k_build<<<NBUCK, 256, 0, stream>>>(bcur, ebuf, rowinfo, dinv, esrc);
    // layer-1 agg fused with layer-2 matmul (h2 -> hbf2, aliases dead ebuf)
    k_aggmm<<<NN / 32, 256, 0, stream>>>(rowinfo, esrc, hbf, dinv, b1, alpha, W2, hbf2);
    // layer-2 aggregation -> fp32 out
    k_agg2<<<NN / 32, 256, 0, stream>>>(rowinfo, esrc, hbf2, dinv, b2, alpha, out);
}

// Round 6
// 209.595 us; speedup vs baseline: 1.0970x; 1.0173x over previous
//
#include <hip/hip_runtime.h>
#include <hip/hip_bf16.h>

#define NN 100000
#define NE 1600000
#define NBUCK 391   // ceil(NN / 256)
#define CAP 5056    // per-bucket edge capacity (expected 4096, sigma~64; mean+15sigma)
#define CHUNK 2048
#define PBLOCKS 782   // ceil(NE / CHUNK)
#define MMBLOCKS 1563 // ceil(NN / 64)
#define BCUR_STRIDE 16  // one counter per 64B line to kill same-line atomic serialization
#define SESZ 1024       // per-block staged-edge capacity (avg 512, sigma 22.6; +22σ)

typedef __attribute__((ext_vector_type(8))) short short8;
typedef __attribute__((ext_vector_type(4))) float f32x4;

static __device__ __forceinline__ unsigned short f2bf(float f) {
    unsigned u = __float_as_uint(f);
    unsigned r = (u + 0x7fffu + ((u >> 16) & 1u)) >> 16;
    return (unsigned short)r;
}
static __device__ __forceinline__ float bf_lo(unsigned u) {
    return __uint_as_float(u << 16);
}
static __device__ __forceinline__ float bf_hi(unsigned u) {
    return __uint_as_float(u & 0xffff0000u);
}
static __device__ __forceinline__ void acc8(float* acc, uint4 v, float nm) {
    acc[0] += bf_lo(v.x) * nm; acc[1] += bf_hi(v.x) * nm;
    acc[2] += bf_lo(v.y) * nm; acc[3] += bf_hi(v.y) * nm;
    acc[4] += bf_lo(v.z) * nm; acc[5] += bf_hi(v.z) * nm;
    acc[6] += bf_lo(v.w) * nm; acc[7] += bf_hi(v.w) * nm;
}
static __device__ __forceinline__ void acc8a(float* acc, uint4 v) {
    acc[0] += bf_lo(v.x); acc[1] += bf_hi(v.x);
    acc[2] += bf_lo(v.y); acc[3] += bf_hi(v.y);
    acc[4] += bf_lo(v.z); acc[5] += bf_hi(v.z);
    acc[6] += bf_lo(v.w); acc[7] += bf_hi(v.w);
}

// ---- global-path aggregation (fallback when a block's edge span > SESZ) -----
// SCALED=true: h rows are pre-scaled by dinv[src]; no per-edge dinv gather.
// hb is the per-lane byte base (h + sl*16B); row byte offset = src << 7.
template<bool SCALED>
static __device__ __forceinline__ void agg_loop(const unsigned char* hb,
                                                const int* __restrict__ esrc,
                                                const float* __restrict__ dinv,
                                                int start, int cnt, float dn,
                                                float* acc) {
    int i = 0;
    for (; i + 4 <= cnt; i += 4) {
        int s0 = esrc[start + i];
        int s1 = esrc[start + i + 1];
        int s2 = esrc[start + i + 2];
        int s3 = esrc[start + i + 3];
        uint4 w0 = *(const uint4*)(hb + ((unsigned)s0 << 7));
        uint4 w1 = *(const uint4*)(hb + ((unsigned)s1 << 7));
        uint4 w2 = *(const uint4*)(hb + ((unsigned)s2 << 7));
        uint4 w3 = *(const uint4*)(hb + ((unsigned)s3 << 7));
        if constexpr (SCALED) {
            acc8a(acc, w0); acc8a(acc, w1); acc8a(acc, w2); acc8a(acc, w3);
        } else {
            float n0 = dinv[s0] * dn, n1 = dinv[s1] * dn;
            float n2 = dinv[s2] * dn, n3 = dinv[s3] * dn;
            acc8(acc, w0, n0); acc8(acc, w1, n1); acc8(acc, w2, n2); acc8(acc, w3, n3);
        }
    }
    for (; i < cnt; ++i) {
        int s0 = esrc[start + i];
        uint4 w0 = *(const uint4*)(hb + ((unsigned)s0 << 7));
        if constexpr (SCALED) {
            acc8a(acc, w0);
        } else {
            float n0 = dinv[s0] * dn;
            acc8(acc, w0, n0);
        }
    }
}

// ---------- FAT: blocks [0,PBLOCKS) = edge partition (1-pass); rest = x@W1 ----
// bucket = dst >> 8; pack = (src<<8)|(dst&255)
// R1-proven: padded bcur (1 counter/line) + LDS bucket-sort so ebuf stores go
// out bucket-major (wave store ~12 lines instead of 64).
__global__ __launch_bounds__(256) void k_fat(const int* __restrict__ ei,
                                             int* __restrict__ bcur,
                                             unsigned* __restrict__ ebuf,
                                             const float* __restrict__ x,
                                             const float* __restrict__ W1,
                                             unsigned short* __restrict__ hout) {
    __shared__ __attribute__((aligned(16))) unsigned char smem[19584];  // max(mm Wt 17408, part 19532)
    int tid = threadIdx.x;
    if (blockIdx.x < PBLOCKS) {
        // layout: lexc[391]@0 (counts then exclusive scan), lbase[391]@1564,
        // sv[2048]@3128, sd[2048]@11320, wscan[4]@19512, sTot@19528
        int* lexc  = (int*)smem;
        int* lbase = (int*)(smem + 1564);
        unsigned* sv = (unsigned*)(smem + 3128);
        int* sd    = (int*)(smem + 11320);
        int* wscan = (int*)(smem + 19512);
        int* sTot  = (int*)(smem + 19528);

        int e0 = blockIdx.x * CHUNK;
        for (int i = tid; i < NBUCK; i += 256) lexc[i] = 0;
        __syncthreads();
        int bs[8]; int rs[8]; unsigned ps[8];
        #pragma unroll
        for (int k = 0; k < 8; ++k) {
            int e = e0 + k * 256 + tid;
            bs[k] = -1;
            if (e < NE) {
                int d = ei[NE + e];
                int s = ei[e];
                int b = d >> 8;
                bs[k] = b;
                rs[k] = atomicAdd(&lexc[b], 1);     // local rank (single LDS pass)
                ps[k] = ((unsigned)s << 8) | (unsigned)(d & 255);
            }
        }
        __syncthreads();
        // thread t owns buckets 2t, 2t+1: block-wide exclusive scan of counts
        int b0i = 2 * tid, b1i = 2 * tid + 1;
        int c0 = (b0i < NBUCK) ? lexc[b0i] : 0;
        int c1 = (b1i < NBUCK) ? lexc[b1i] : 0;
        int v = c0 + c1;
        int lane = tid & 63;
        int incl = v;
        #pragma unroll
        for (int off = 1; off < 64; off <<= 1) {
            int t = __shfl_up(incl, off, 64);
            if (lane >= off) incl += t;
        }
        if (lane == 63) wscan[tid >> 6] = incl;
        // global within-bucket offsets (padded: each counter on its own 64B line)
        int gb0 = 0, gb1 = 0;
        if (c0) gb0 = atomicAdd(&bcur[b0i * BCUR_STRIDE], c0);
        if (c1) gb1 = atomicAdd(&bcur[b1i * BCUR_STRIDE], c1);
        __syncthreads();
        if (tid == 0) {
            int a = 0;
            #pragma unroll
            for (int w = 0; w < 4; ++w) { int t = wscan[w]; wscan[w] = a; a += t; }
            *sTot = a;
        }
        __syncthreads();
        int ex = incl - v + wscan[tid >> 6];
        if (b0i < NBUCK) { lexc[b0i] = ex;      lbase[b0i] = gb0; }
        if (b1i < NBUCK) { lexc[b1i] = ex + c0; lbase[b1i] = gb1; }
        __syncthreads();
        // scatter into LDS, bucket-major
        #pragma unroll
        for (int k = 0; k < 8; ++k) {
            if (bs[k] >= 0) {
                int b = bs[k];
                int slot = lexc[b] + rs[k];
                int pos  = lbase[b] + rs[k];
                sv[slot] = ps[k];
                sd[slot] = (pos < CAP) ? b * CAP + pos : -1;  // safety clamp; never hit
            }
        }
        __syncthreads();
        int V = *sTot;
        for (int j = tid; j < V; j += 256) {
            int d = sd[j];
            if (d >= 0) ebuf[d] = sv[j];
        }
    } else {
        // ---- mm128: h1 = x @ W1 -> bf16 (64 rows/block, R1-proven) ----
        constexpr int K = 128, KP = K + 8;
        unsigned short* Wt = (unsigned short*)smem;  // 64 * 136
        for (int idx = tid; idx < K * 64; idx += 256) {
            int k = idx >> 6, n = idx & 63;
            Wt[n * KP + k] = f2bf(W1[idx]);
        }
        __syncthreads();
        int wave = tid >> 6, lane = tid & 63;
        int m = lane & 15, q = lane >> 4;
        int n0 = (blockIdx.x - PBLOCKS) * 64 + wave * 16;
        f32x4 acc[4] = {{0.f,0.f,0.f,0.f},{0.f,0.f,0.f,0.f},{0.f,0.f,0.f,0.f},{0.f,0.f,0.f,0.f}};
        int row = n0 + m;
        int rowc = row < NN ? row : NN - 1;
        const float* xr = x + (long)rowc * K;
        #pragma unroll
        for (int kk = 0; kk < K / 32; ++kk) {
            const float4* p = (const float4*)(xr + kk * 32 + q * 8);
            float4 v0 = p[0], v1 = p[1];
            float xv[8] = {v0.x, v0.y, v0.z, v0.w, v1.x, v1.y, v1.z, v1.w};
            short8 afrag;
            #pragma unroll
            for (int i2 = 0; i2 < 8; ++i2) afrag[i2] = (short)f2bf(xv[i2]);
            #pragma unroll
            for (int nt = 0; nt < 4; ++nt) {
                const short8* bp = (const short8*)&Wt[(nt * 16 + m) * KP + kk * 32 + q * 8];
                acc[nt] = __builtin_amdgcn_mfma_f32_16x16x32_bf16(afrag, *bp, acc[nt], 0, 0, 0);
            }
        }
        // D layout: col=lane&15, row=(lane>>4)*4+reg  [m89-verified]
        #pragma unroll
        for (int reg = 0; reg < 4; ++reg) {
            int node = n0 + q * 4 + reg;
            if (node < NN) {
                #pragma unroll
                for (int nt = 0; nt < 4; ++nt)
                    hout[(long)node * 64 + nt * 16 + m] = f2bf(acc[nt][reg]);
            }
        }
    }
}

// one block (256 thr) per bucket, single ebuf pass with register stash.
// edges within each node's segment are sorted by src-tile (tile = src>>14)
// key = (dst_local<<3)|tile; kstart[key] = start.
// rowinfo[node] = (start << 11) | degree   (start < 2^21, deg < 2^11)
__global__ __launch_bounds__(256) void k_build(const int* __restrict__ bcur,
                                               const unsigned* __restrict__ ebuf,
                                               unsigned* __restrict__ rowinfo,
                                               float* __restrict__ dinv,
                                               int* __restrict__ esrc) {
    __shared__ int cnt[2048];
    __shared__ int kstart[2048];
    __shared__ int wsum[4];
    int tid = threadIdx.x;
    int base = blockIdx.x * CAP;
    int nedge = bcur[blockIdx.x * BCUR_STRIDE];
    if (nedge > CAP) nedge = CAP;
    #pragma unroll
    for (int t = 0; t < 8; ++t) cnt[(tid << 3) | t] = 0;
    __syncthreads();
    int st[20];      // (rank<<11) | key, or -1
    int ssrc[20];    // src node id
    #pragma unroll
    for (int k = 0; k < 20; ++k) {
        int j = tid + k * 256;
        st[k] = -1;
        if (j < nedge) {
            unsigned p = ebuf[base + j];
            int dl = (int)(p & 255u);
            int s = (int)(p >> 8);
            int key = (dl << 3) | (s >> 14);
            int r = atomicAdd(&cnt[key], 1);
            st[k] = (r << 11) | key;
            ssrc[k] = s;
        }
    }
    __syncthreads();
    // thread tid owns node tid: serial scan over its 8 tile counts
    int c[8];
    int v = 0;
    #pragma unroll
    for (int t = 0; t < 8; ++t) { c[t] = cnt[(tid << 3) | t]; v += c[t]; }
    int lane = tid & 63;
    int incl = v;
    #pragma unroll
    for (int off = 1; off < 64; off <<= 1) {
        int t = __shfl_up(incl, off, 64);
        if (lane >= off) incl += t;
    }
    if (lane == 63) wsum[tid >> 6] = incl;
    __syncthreads();
    if (tid == 0) {
        int a = 0;
        #pragma unroll
        for (int w = 0; w < 4; ++w) { int t = wsum[w]; wsum[w] = a; a += t; }
    }
    __syncthreads();
    int ex = incl - v + wsum[tid >> 6];
    int node = blockIdx.x * 256 + tid;
    if (node < NN) {
        rowinfo[node] = ((unsigned)(base + ex) << 11) | (unsigned)v;
        dinv[node] = rsqrtf((float)(v + 1));  // +1 self-loop
    }
    int off = base + ex;
    #pragma unroll
    for (int t = 0; t < 8; ++t) { kstart[(tid << 3) | t] = off; off += c[t]; }
    __syncthreads();
    #pragma unroll
    for (int k = 0; k < 20; ++k) {
        if (st[k] >= 0)
            esrc[kstart[st[k] & 2047] + (st[k] >> 11)] = ssrc[k];
    }
}

// ---------- fused: layer-1 agg (32 nodes/block) + h2 = prelu(agg1)@W2 --------
// NN % 32 == 0 so every block is full.
// NEW: the block's 32 nodes have CONTIGUOUS esrc segments (exclusive-scan
// layout) -> bulk-stage the whole span into LDS coalesced, then the per-edge
// loop reads the index from LDS (ds_read, ~no latency) and issues the h-row
// gather immediately: ONE global-latency level instead of two (esrc->row).
// h2 output is PRE-SCALED by dinv[node] -> k_agg2 needs no per-edge dinv gather.
__global__ __launch_bounds__(256) void k_aggmm(const unsigned* __restrict__ rowinfo,
                                               const int* __restrict__ esrc,
                                               const unsigned short* __restrict__ h,
                                               const float* __restrict__ dinv,
                                               const float* __restrict__ bias,
                                               const float* __restrict__ alpha,
                                               const float* __restrict__ W2,
                                               unsigned short* __restrict__ hout2) {
    __shared__ unsigned short Wt[64 * 72];    // W2 staged: Wt[n*72+k]
    __shared__ unsigned short aggs[32 * 72];  // 32 node-rows of bf16 agg (+8 pad)
    __shared__ float dnv[32];                 // per-node dinv for epilogue scaling
    __shared__ int se[SESZ];                  // staged edge-src indices
    __shared__ int ssb[2];                    // [span start, span end)
    int tid = threadIdx.x;
    if (tid == 0) ssb[0] = (int)(rowinfo[blockIdx.x * 32] >> 11);
    if (tid == 1) {
        unsigned uu = rowinfo[blockIdx.x * 32 + 31];
        ssb[1] = (int)((uu >> 11) + (uu & 2047u));
    }
    for (int idx = tid; idx < 64 * 64; idx += 256) {
        int k = idx >> 6, n = idx & 63;
        Wt[n * 72 + k] = f2bf(W2[idx]);
    }
    __syncthreads();
    int start0 = ssb[0];
    int count = ssb[1] - start0;
    bool staged = (count <= SESZ);            // fallback never hit statistically
    if (staged) {
        for (int j = tid; j < count; j += 256) se[j] = esrc[start0 + j];
    }
    int sl = tid & 7;
    int ln = tid >> 3;                  // 0..31 local node
    int node = blockIdx.x * 32 + ln;
    unsigned u = rowinfo[node];
    int start = (int)(u >> 11);
    int cnt = (int)(u & 2047u);
    float dn = dinv[node];
    if (sl == 0) dnv[ln] = dn;
    const unsigned char* hb = (const unsigned char*)h + sl * 16;
    __syncthreads();

    float acc[8];
    {   // self-loop
        uint4 hw = *(const uint4*)(hb + ((unsigned)node << 7));
        float d2 = dn * dn;
        acc[0] = bf_lo(hw.x) * d2; acc[1] = bf_hi(hw.x) * d2;
        acc[2] = bf_lo(hw.y) * d2; acc[3] = bf_hi(hw.y) * d2;
        acc[4] = bf_lo(hw.z) * d2; acc[5] = bf_hi(hw.z) * d2;
        acc[6] = bf_lo(hw.w) * d2; acc[7] = bf_hi(hw.w) * d2;
    }
    if (staged) {
        int ls = start - start0;
        int i = 0;
        for (; i + 4 <= cnt; i += 4) {
            int s0 = se[ls + i];
            int s1 = se[ls + i + 1];
            int s2 = se[ls + i + 2];
            int s3 = se[ls + i + 3];
            float n0 = dinv[s0] * dn, n1 = dinv[s1] * dn;
            float n2 = dinv[s2] * dn, n3 = dinv[s3] * dn;
            uint4 w0 = *(const uint4*)(hb + ((unsigned)s0 << 7));
            uint4 w1 = *(const uint4*)(hb + ((unsigned)s1 << 7));
            uint4 w2 = *(const uint4*)(hb + ((unsigned)s2 << 7));
            uint4 w3 = *(const uint4*)(hb + ((unsigned)s3 << 7));
            acc8(acc, w0, n0); acc8(acc, w1, n1); acc8(acc, w2, n2); acc8(acc, w3, n3);
        }
        for (; i < cnt; ++i) {
            int s0 = se[ls + i];
            float n0 = dinv[s0] * dn;
            uint4 w0 = *(const uint4*)(hb + ((unsigned)s0 << 7));
            acc8(acc, w0, n0);
        }
    } else {
        agg_loop<false>(hb, esrc, dinv, start, cnt, dn, acc);
    }

    float4 blo = *(const float4*)(bias + sl * 8);
    float4 bhi = *(const float4*)(bias + sl * 8 + 4);
    float4 alo = *(const float4*)(alpha + sl * 8);
    float4 ahi = *(const float4*)(alpha + sl * 8 + 4);
    float bb[8] = {blo.x, blo.y, blo.z, blo.w, bhi.x, bhi.y, bhi.z, bhi.w};
    float aa[8] = {alo.x, alo.y, alo.z, alo.w, ahi.x, ahi.y, ahi.z, ahi.w};
    #pragma unroll
    for (int j = 0; j < 8; ++j) {
        float v = acc[j] + bb[j];
        acc[j] = v >= 0.f ? v : aa[j] * v;
    }
    uint4 pk;
    pk.x = (unsigned)f2bf(acc[0]) | ((unsigned)f2bf(acc[1]) << 16);
    pk.y = (unsigned)f2bf(acc[2]) | ((unsigned)f2bf(acc[3]) << 16);
    pk.z = (unsigned)f2bf(acc[4]) | ((unsigned)f2bf(acc[5]) << 16);
    pk.w = (unsigned)f2bf(acc[6]) | ((unsigned)f2bf(acc[7]) << 16);
    *(uint4*)&aggs[ln * 72 + sl * 8] = pk;
    __syncthreads();

    // MFMA: waves 0,1 compute 16 rows each: [16x64] @ [64x64]
    int wave = tid >> 6;
    if (wave < 2) {
        int lane = tid & 63;
        int m = lane & 15, q = lane >> 4;
        int row = wave * 16 + m;
        f32x4 c2[4] = {{0.f,0.f,0.f,0.f},{0.f,0.f,0.f,0.f},{0.f,0.f,0.f,0.f},{0.f,0.f,0.f,0.f}};
        #pragma unroll
        for (int kk = 0; kk < 2; ++kk) {
            short8 afrag = *(const short8*)&aggs[row * 72 + kk * 32 + q * 8];
            #pragma unroll
            for (int nt = 0; nt < 4; ++nt) {
                const short8* bp = (const short8*)&Wt[(nt * 16 + m) * 72 + kk * 32 + q * 8];
                c2[nt] = __builtin_amdgcn_mfma_f32_16x16x32_bf16(afrag, *bp, c2[nt], 0, 0, 0);
            }
        }
        #pragma unroll
        for (int reg = 0; reg < 4; ++reg) {
            int rr = wave * 16 + q * 4 + reg;
            int nd = blockIdx.x * 32 + rr;
            float dv = dnv[rr];
            #pragma unroll
            for (int nt = 0; nt < 4; ++nt)
                hout2[(long)nd * 64 + nt * 16 + m] = f2bf(c2[nt][reg] * dv);
        }
    }
}

// ---------- final aggregation: 8 lanes/node, fp32 out ------------------------
// h is pre-scaled by dinv[src]: per-edge work = load + unpack-add only;
// uniform dn applied once at the end. Same LDS edge-index staging as k_aggmm.
__global__ __launch_bounds__(256) void k_agg2(const unsigned* __restrict__ rowinfo,
                                              const int* __restrict__ esrc,
                                              const unsigned short* __restrict__ h,
                                              const float* __restrict__ dinv,
                                              const float* __restrict__ bias,
                                              const float* __restrict__ alpha,
                                              float* __restrict__ out) {
    __shared__ int se[SESZ];
    __shared__ int ssb[2];
    int tid = threadIdx.x;
    if (tid == 0) ssb[0] = (int)(rowinfo[blockIdx.x * 32] >> 11);
    if (tid == 1) {
        unsigned uu = rowinfo[blockIdx.x * 32 + 31];
        ssb[1] = (int)((uu >> 11) + (uu & 2047u));
    }
    __syncthreads();
    int start0 = ssb[0];
    int count = ssb[1] - start0;
    bool staged = (count <= SESZ);
    if (staged) {
        for (int j = tid; j < count; j += 256) se[j] = esrc[start0 + j];
    }
    int sl = tid & 7;
    int node = blockIdx.x * 32 + (tid >> 3);
    unsigned u = rowinfo[node];
    int start = (int)(u >> 11);
    int cnt = (int)(u & 2047u);
    float dn = dinv[node];
    const unsigned char* hb = (const unsigned char*)h + sl * 16;
    __syncthreads();

    float acc[8];
    {   // self-loop: h[node] already carries dinv[node]; one more *dn at the end
        uint4 hw = *(const uint4*)(hb + ((unsigned)node << 7));
        acc[0] = bf_lo(hw.x); acc[1] = bf_hi(hw.x);
        acc[2] = bf_lo(hw.y); acc[3] = bf_hi(hw.y);
        acc[4] = bf_lo(hw.z); acc[5] = bf_hi(hw.z);
        acc[6] = bf_lo(hw.w); acc[7] = bf_hi(hw.w);
    }
    if (staged) {
        int ls = start - start0;
        int i = 0;
        for (; i + 4 <= cnt; i += 4) {
            int s0 = se[ls + i];
            int s1 = se[ls + i + 1];
            int s2 = se[ls + i + 2];
            int s3 = se[ls + i + 3];
            uint4 w0 = *(const uint4*)(hb + ((unsigned)s0 << 7));
            uint4 w1 = *(const uint4*)(hb + ((unsigned)s1 << 7));
            uint4 w2 = *(const uint4*)(hb + ((unsigned)s2 << 7));
            uint4 w3 = *(const uint4*)(hb + ((unsigned)s3 << 7));
            acc8a(acc, w0); acc8a(acc, w1); acc8a(acc, w2); acc8a(acc, w3);
        }
        for (; i < cnt; ++i) {
            int s0 = se[ls + i];
            uint4 w0 = *(const uint4*)(hb + ((unsigned)s0 << 7));
            acc8a(acc, w0);
        }
    } else {
        agg_loop<true>(hb, esrc, dinv, start, cnt, dn, acc);
    }

    float4 blo = *(const float4*)(bias + sl * 8);
    float4 bhi = *(const float4*)(bias + sl * 8 + 4);
    float4 alo = *(const float4*)(alpha + sl * 8);
    float4 ahi = *(const float4*)(alpha + sl * 8 + 4);
    float bb[8] = {blo.x, blo.y, blo.z, blo.w, bhi.x, bhi.y, bhi.z, bhi.w};
    float aa[8] = {alo.x, alo.y, alo.z, alo.w, ahi.x, ahi.y, ahi.z, ahi.w};
    #pragma unroll
    for (int j = 0; j < 8; ++j) {
        float v = acc[j] * dn + bb[j];
        acc[j] = v >= 0.f ? v : aa[j] * v;
    }
    float* op = out + (long)node * 64 + sl * 8;
    *(float4*)op = make_float4(acc[0], acc[1], acc[2], acc[3]);
    *(float4*)(op + 4) = make_float4(acc[4], acc[5], acc[6], acc[7]);
}

extern "C" void kernel_launch(void* const* d_in, const int* in_sizes, int n_in,
                              void* d_out, int out_size, void* d_ws, size_t ws_size,
                              hipStream_t stream) {
    const float* x     = (const float*)d_in[0];
    const int*   ei    = (const int*)d_in[1];
    const float* W1    = (const float*)d_in[2];
    const float* b1    = (const float*)d_in[3];
    const float* W2    = (const float*)d_in[4];
    const float* b2    = (const float*)d_in[5];
    const float* alpha = (const float*)d_in[6];
    float* out = (float*)d_out;

    char* ws = (char*)d_ws;
    float*    dinv      = (float*)(ws);                      //        0: 400,384
    unsigned* rowinfo   = (unsigned*)(ws + 400384);          //   400384: 400,384
    int*      bcur      = (int*)(ws + 800768);               //   800768: 25,088 (391*64B, padded)
    int*      esrc      = (int*)(ws + 825856);               //   825856: 7,907,584 (391*CAP*4)
    unsigned short* hbf = (unsigned short*)(ws + 8733440);   //  8733440: 12,800,000
    unsigned* ebuf      = (unsigned*)(ws + 21533440);        // 21533440: region max(7.9M, 12.8M)
    unsigned short* hbf2 = (unsigned short*)(ws + 21533440); // alias ebuf (dead after k_build)
    // total: 34,333,440 B

    (void)hipMemsetAsync(bcur, 0, NBUCK * BCUR_STRIDE * sizeof(int), stream);
    // edge partition (782 blocks, single-pass) overlapped with x@W1 (1563 blocks)
    k_fat<<<PBLOCKS + MMBLOCKS, 256, 0, stream>>>(ei, bcur, ebuf, x, W1, hbf);
    k_build<<<NBUCK, 256, 0, stream>>>(bcur, ebuf, rowinfo, dinv, esrc);
    // layer-1 agg fused with layer-2 matmul (h2 -> hbf2, aliases dead ebuf)
    k_aggmm<<<NN / 32, 256, 0, stream>>>(rowinfo, esrc, hbf, dinv, b1, alpha, W2, hbf2);
    // layer-2 aggregation -> fp32 out
    k_agg2<<<NN / 32, 256, 0, stream>>>(rowinfo, esrc, hbf2, dinv, b2, alpha, out);
}